// Round 2
// baseline (1118.584 us; speedup 1.0000x reference)
//
#include <hip/hip_runtime.h>

// Segmented GroupNorm: N rows x C=128 channels, G=32 groups, Cg=4.
// group g == float4 element index (i & 31); channels 4g..4g+3.
// Pass 1: per-(seg,group) sum/sumsq via LDS bins (native ds_add_f32) + native
//         global f32 atomic flush.
// Finalize: mean/inv per (seg,group) -> float2 table.
// Pass 2: elementwise normalize, stats staged in LDS (SoA), nontemporal stores.

#define C_CHANNELS 128
#define GROUPS 32
#define SEG_CAP 256        // global bin capacity (ws)
#define LDS_SEG_CAP 104    // per-block LDS bin capacity (S=100 fits); 27KB LDS -> 6 blocks/CU
#define EPS 1e-5f

// Native vector type for nontemporal stores (__builtin_nontemporal_store
// rejects HIP_vector_type).
typedef float f32x4 __attribute__((ext_vector_type(4)));

// Native LDS fp32 atomic add, fire-and-forget (no return, no lgkm tracking by
// compiler -> explicit s_waitcnt before the barrier). Flat LDS aperture is
// 4GB-aligned, so the low 32 bits of a generic pointer to __shared__ are the
// DS byte offset.
__device__ __forceinline__ void lds_fadd(float* p, float v) {
    asm volatile("ds_add_f32 %0, %1"
                 :: "v"((unsigned)(unsigned long long)p), "v"(v));
}

__device__ __forceinline__ void nt_store4(float4* p, const float4& v) {
    f32x4 t; t.x = v.x; t.y = v.y; t.z = v.z; t.w = v.w;
    __builtin_nontemporal_store(t, (f32x4*)p);
}

__global__ __launch_bounds__(256) void gn_pass1(
    const float4* __restrict__ x, const int* __restrict__ seg,
    float* __restrict__ gsum, float* __restrict__ gsq, float* __restrict__ gcnt,
    const int* __restrict__ nInstPtr, int N)
{
    __shared__ float lsum[LDS_SEG_CAP * GROUPS];
    __shared__ float lsq [LDS_SEG_CAP * GROUPS];
    __shared__ float lcnt[LDS_SEG_CAP];

    for (int t = threadIdx.x; t < LDS_SEG_CAP * GROUPS; t += blockDim.x) {
        lsum[t] = 0.f; lsq[t] = 0.f;
    }
    for (int t = threadIdx.x; t < LDS_SEG_CAP; t += blockDim.x) lcnt[t] = 0.f;
    __syncthreads();

    const int g = threadIdx.x & 31;               // group id, loop-invariant
    const long long total  = (long long)N * GROUPS;
    const long long stride = (long long)gridDim.x * blockDim.x;   // multiple of 32
    const int rowStride = (int)(stride >> 5);
    long long i = (long long)blockIdx.x * blockDim.x + threadIdx.x;

    // x4 unrolled: four independent 16B loads + four seg loads in flight
    for (; i + 3 * stride < total; i += 4 * stride) {
        int row0 = (int)(i >> 5);
        float4 v0 = x[i];
        float4 v1 = x[i + stride];
        float4 v2 = x[i + 2 * stride];
        float4 v3 = x[i + 3 * stride];
        int s0 = seg[row0];
        int s1 = seg[row0 + rowStride];
        int s2 = seg[row0 + 2 * rowStride];
        int s3 = seg[row0 + 3 * rowStride];

        float a0 = (v0.x + v0.y) + (v0.z + v0.w);
        float q0 = v0.x*v0.x + v0.y*v0.y + v0.z*v0.z + v0.w*v0.w;
        float a1 = (v1.x + v1.y) + (v1.z + v1.w);
        float q1 = v1.x*v1.x + v1.y*v1.y + v1.z*v1.z + v1.w*v1.w;
        float a2 = (v2.x + v2.y) + (v2.z + v2.w);
        float q2 = v2.x*v2.x + v2.y*v2.y + v2.z*v2.z + v2.w*v2.w;
        float a3 = (v3.x + v3.y) + (v3.z + v3.w);
        float q3 = v3.x*v3.x + v3.y*v3.y + v3.z*v3.z + v3.w*v3.w;

        if (s0 < LDS_SEG_CAP) {
            lds_fadd(&lsum[s0 * GROUPS + g], a0);
            lds_fadd(&lsq [s0 * GROUPS + g], q0);
            if (g == 0) lds_fadd(&lcnt[s0], 1.0f);
        } else {
            unsafeAtomicAdd(&gsum[s0 * GROUPS + g], a0);
            unsafeAtomicAdd(&gsq [s0 * GROUPS + g], q0);
            if (g == 0) unsafeAtomicAdd(&gcnt[s0], 1.0f);
        }
        if (s1 < LDS_SEG_CAP) {
            lds_fadd(&lsum[s1 * GROUPS + g], a1);
            lds_fadd(&lsq [s1 * GROUPS + g], q1);
            if (g == 0) lds_fadd(&lcnt[s1], 1.0f);
        } else {
            unsafeAtomicAdd(&gsum[s1 * GROUPS + g], a1);
            unsafeAtomicAdd(&gsq [s1 * GROUPS + g], q1);
            if (g == 0) unsafeAtomicAdd(&gcnt[s1], 1.0f);
        }
        if (s2 < LDS_SEG_CAP) {
            lds_fadd(&lsum[s2 * GROUPS + g], a2);
            lds_fadd(&lsq [s2 * GROUPS + g], q2);
            if (g == 0) lds_fadd(&lcnt[s2], 1.0f);
        } else {
            unsafeAtomicAdd(&gsum[s2 * GROUPS + g], a2);
            unsafeAtomicAdd(&gsq [s2 * GROUPS + g], q2);
            if (g == 0) unsafeAtomicAdd(&gcnt[s2], 1.0f);
        }
        if (s3 < LDS_SEG_CAP) {
            lds_fadd(&lsum[s3 * GROUPS + g], a3);
            lds_fadd(&lsq [s3 * GROUPS + g], q3);
            if (g == 0) lds_fadd(&lcnt[s3], 1.0f);
        } else {
            unsafeAtomicAdd(&gsum[s3 * GROUPS + g], a3);
            unsafeAtomicAdd(&gsq [s3 * GROUPS + g], q3);
            if (g == 0) unsafeAtomicAdd(&gcnt[s3], 1.0f);
        }
    }
    // tail
    for (; i < total; i += stride) {
        int row = (int)(i >> 5);
        float4 v = x[i];
        int s = seg[row];
        float a = (v.x + v.y) + (v.z + v.w);
        float q = v.x*v.x + v.y*v.y + v.z*v.z + v.w*v.w;
        if (s < LDS_SEG_CAP) {
            lds_fadd(&lsum[s * GROUPS + g], a);
            lds_fadd(&lsq [s * GROUPS + g], q);
            if (g == 0) lds_fadd(&lcnt[s], 1.0f);
        } else {
            unsafeAtomicAdd(&gsum[s * GROUPS + g], a);
            unsafeAtomicAdd(&gsq [s * GROUPS + g], q);
            if (g == 0) unsafeAtomicAdd(&gcnt[s], 1.0f);
        }
    }

    // drain our untracked ds_add_f32 ops before the barrier, then flush
    asm volatile("s_waitcnt lgkmcnt(0)" ::: "memory");
    __syncthreads();

    int S = *nInstPtr;
    int lim = min(S, LDS_SEG_CAP);
    int nb = lim * GROUPS;
    int rot = (int)((blockIdx.x * 64u) % (unsigned)nb);
    for (int t = threadIdx.x; t < nb; t += blockDim.x) {
        int j = t + rot; if (j >= nb) j -= nb;
        float a = lsum[j], b = lsq[j];
        if (a != 0.f || b != 0.f) {
            unsafeAtomicAdd(&gsum[j], a);
            unsafeAtomicAdd(&gsq [j], b);
        }
    }
    for (int t = threadIdx.x; t < lim; t += blockDim.x) {
        float c = lcnt[t];
        if (c != 0.f) unsafeAtomicAdd(&gcnt[t], c);
    }
}

__global__ __launch_bounds__(256) void gn_finalize(
    const float* __restrict__ gsum, const float* __restrict__ gsq,
    const float* __restrict__ gcnt, float2* __restrict__ stats,
    const int* __restrict__ nInstPtr)
{
    int S = *nInstPtr;
    int i = blockIdx.x * blockDim.x + threadIdx.x;
    if (i < S * GROUPS) {
        int s = i >> 5;
        float cnt = gcnt[s];
        float denom = fmaxf(cnt * 4.0f, 1.0f);
        float mean = gsum[i] / denom;
        float var  = gsq[i] / denom - mean * mean;
        float inv  = rsqrtf(var + EPS);
        stats[i] = make_float2(mean, inv);
    }
}

__global__ __launch_bounds__(256) void gn_pass2(
    const float4* __restrict__ x, const int* __restrict__ seg,
    const float2* __restrict__ stats,
    const float4* __restrict__ gamma4, const float4* __restrict__ beta4,
    float4* __restrict__ out, const int* __restrict__ nInstPtr, int N)
{
    // Stage stats in LDS as SoA: bank index == group -> conflict-free reads,
    // immune to L1 thrash from the streaming x/out traffic.
    __shared__ float lmean[LDS_SEG_CAP * GROUPS];
    __shared__ float linv [LDS_SEG_CAP * GROUPS];
    int S = *nInstPtr;
    int lim = min(S, LDS_SEG_CAP) * GROUPS;
    for (int t = threadIdx.x; t < lim; t += blockDim.x) {
        float2 mi = stats[t];
        lmean[t] = mi.x; linv[t] = mi.y;
    }
    __syncthreads();

    const int g = threadIdx.x & 31;               // loop-invariant group id
    const float4 gm = gamma4[g];
    const float4 bt = beta4[g];
    const long long total  = (long long)N * GROUPS;
    const long long stride = (long long)gridDim.x * blockDim.x;
    const int rowStride = (int)(stride >> 5);
    long long i = (long long)blockIdx.x * blockDim.x + threadIdx.x;

    for (; i + stride < total; i += 2 * stride) {
        int row0 = (int)(i >> 5);
        float4 v0 = x[i];
        float4 v1 = x[i + stride];
        int s0 = seg[row0];
        int s1 = seg[row0 + rowStride];

        float m0, iv0, m1, iv1;
        if (s0 < LDS_SEG_CAP) { m0 = lmean[s0 * GROUPS + g]; iv0 = linv[s0 * GROUPS + g]; }
        else { float2 t = stats[s0 * GROUPS + g]; m0 = t.x; iv0 = t.y; }
        if (s1 < LDS_SEG_CAP) { m1 = lmean[s1 * GROUPS + g]; iv1 = linv[s1 * GROUPS + g]; }
        else { float2 t = stats[s1 * GROUPS + g]; m1 = t.x; iv1 = t.y; }

        float4 o0, o1;
        o0.x = (v0.x - m0) * iv0 * gm.x + bt.x;
        o0.y = (v0.y - m0) * iv0 * gm.y + bt.y;
        o0.z = (v0.z - m0) * iv0 * gm.z + bt.z;
        o0.w = (v0.w - m0) * iv0 * gm.w + bt.w;
        o1.x = (v1.x - m1) * iv1 * gm.x + bt.x;
        o1.y = (v1.y - m1) * iv1 * gm.y + bt.y;
        o1.z = (v1.z - m1) * iv1 * gm.z + bt.z;
        o1.w = (v1.w - m1) * iv1 * gm.w + bt.w;

        // nontemporal: out is write-once dead data; don't evict features from L3
        nt_store4(&out[i], o0);
        nt_store4(&out[i + stride], o1);
    }
    for (; i < total; i += stride) {
        int row = (int)(i >> 5);
        float4 v = x[i];
        int s = seg[row];
        float m, iv;
        if (s < LDS_SEG_CAP) { m = lmean[s * GROUPS + g]; iv = linv[s * GROUPS + g]; }
        else { float2 t = stats[s * GROUPS + g]; m = t.x; iv = t.y; }
        float4 o;
        o.x = (v.x - m) * iv * gm.x + bt.x;
        o.y = (v.y - m) * iv * gm.y + bt.y;
        o.z = (v.z - m) * iv * gm.z + bt.z;
        o.w = (v.w - m) * iv * gm.w + bt.w;
        nt_store4(&out[i], o);
    }
}

extern "C" void kernel_launch(void* const* d_in, const int* in_sizes, int n_in,
                              void* d_out, int out_size, void* d_ws, size_t ws_size,
                              hipStream_t stream) {
    const float* feat  = (const float*)d_in[0];
    const int*   seg   = (const int*)d_in[1];
    const float* gamma = (const float*)d_in[2];
    const float* beta  = (const float*)d_in[3];
    const int*   nInst = (const int*)d_in[4];
    const int N = in_sizes[0] / C_CHANNELS;

    // ws layout: gsum [SEG_CAP*32]f | gsq [SEG_CAP*32]f | gcnt [SEG_CAP]f | stats [SEG_CAP*32]float2
    float* gsum = (float*)d_ws;                                   // 32768 B
    float* gsq  = gsum + SEG_CAP * GROUPS;                        // 32768 B
    float* gcnt = gsq  + SEG_CAP * GROUPS;                        // 1024 B
    float2* stats = (float2*)(gcnt + SEG_CAP);                    // 8-aligned
    size_t zero_bytes = (size_t)(2 * SEG_CAP * GROUPS + SEG_CAP) * sizeof(float);

    (void)hipMemsetAsync(d_ws, 0, zero_bytes, stream);

    // 1536 blocks = 6 blocks/CU (LDS-limited), all resident, uniform work
    gn_pass1<<<1536, 256, 0, stream>>>(
        (const float4*)feat, seg, gsum, gsq, gcnt, nInst, N);

    gn_finalize<<<(SEG_CAP * GROUPS + 255) / 256, 256, 0, stream>>>(
        gsum, gsq, gcnt, stats, nInst);

    gn_pass2<<<1536, 256, 0, stream>>>(
        (const float4*)feat, seg, stats,
        (const float4*)gamma, (const float4*)beta,
        (float4*)d_out, nInst, N);
}